// Round 4
// baseline (150.800 us; speedup 1.0000x reference)
//
#include <hip/hip_runtime.h>

// ---------------------------------------------------------------------------
// MoE with adaptive gate, B=8192 D=2048 E=8 H=128, fp32 in/out, bf16 MFMA core
// GEMM1: split-K (2 halves), 256x256 blocks, gemm3-clone core -> bf16 partials
// GEMM2: merge partials + silu + W2 GEMM + gate-scale  (memory-bound)
// GEMM3: 256x256 counted-vmcnt core (round-3 structure + setprio)
// ---------------------------------------------------------------------------

typedef __attribute__((ext_vector_type(8))) short short8;   // 8 bf16 (4 VGPRs)
typedef __attribute__((ext_vector_type(4))) float f32x4;    // MFMA C/D

#define B_SZ 8192
#define D_SZ 2048
#define E_SZ 8
#define H_SZ 128

#define VMCNT(n) asm volatile("s_waitcnt vmcnt(" #n ")" ::: "memory")
#define BAR()    __builtin_amdgcn_s_barrier()

__device__ __forceinline__ short f2bf(float f) {
  unsigned u = __builtin_bit_cast(unsigned, f);
  unsigned r = (u + 0x7fffu + ((u >> 16) & 1u)) >> 16;   // RNE
  return (short)r;
}

__device__ __forceinline__ float bf2f(short s) {
  return __builtin_bit_cast(float, (unsigned)((unsigned short)s) << 16);
}

__device__ __forceinline__ float silu_f(float v) {
  return v / (1.f + __expf(-v));
}

__device__ __forceinline__ void gload_lds16(const void* g, void* l) {
  __builtin_amdgcn_global_load_lds(
      (const __attribute__((address_space(1))) void*)g,
      (__attribute__((address_space(3))) void*)l,
      16, 0, 0);
}

// ---------------------------------------------------------------------------
// Shared 256x256 core: 512 thr, 8 waves (2M x 4N), wave-out 128x64, acc[8][4].
// 4 tile streams (A0,A1 = row-halves; B0,B1 = col-halves), frag tiles of 8192
// shorts: elem = kg*1024 + p*8 + j, k = tau*64 + kg*8 + j.
// LDS 128 KB = 2 bufs x (A0|A1|B0|B1) x 16 KB.  2 subphases per K-tile,
// 4 loads/thread/subphase, VMCNT(4) + 1 barrier per subphase.
// ---------------------------------------------------------------------------
template<int NKT>
__device__ __forceinline__ void core256(const short* __restrict__ A0,
                                        const short* __restrict__ A1,
                                        const short* __restrict__ B0,
                                        const short* __restrict__ B1,
                                        short* lds, f32x4 acc[8][4])
{
  const int tid  = threadIdx.x;
  const int lane = tid & 63;
  const int wid  = tid >> 6;
  const int wm = wid >> 2, wn = wid & 3;
  const int lm = lane & 15, lk = lane >> 4;
  const int wlds = (tid & ~63) * 8;

  auto STAGE = [&](int n2) {
    const int tau = n2 >> 1, ks = n2 & 1, b = tau & 1;
    gload_lds16(A0 + (size_t)tau*8192 + ks*4096 + tid*8,
                lds + b*32768 + ks*4096 + wlds);
    gload_lds16(A1 + (size_t)tau*8192 + ks*4096 + tid*8,
                lds + b*32768 + 8192 + ks*4096 + wlds);
    gload_lds16(B0 + (size_t)tau*8192 + ks*4096 + tid*8,
                lds + b*32768 + 16384 + ks*4096 + wlds);
    gload_lds16(B1 + (size_t)tau*8192 + ks*4096 + tid*8,
                lds + b*32768 + 24576 + ks*4096 + wlds);
  };

  STAGE(0); STAGE(1);
  VMCNT(4); BAR();

  for (int n = 0; n < 2*NKT; ++n) {
    const int ks = n & 1, b = (n >> 1) & 1;
    if (n + 2 < 2*NKT) STAGE(n + 2);
    short8 av[8], bv[4];
    #pragma unroll
    for (int f = 0; f < 8; ++f)
      av[f] = *(const short8*)(lds + b*32768 + wm*8192 + (ks*4+lk)*1024 + (f*16 + lm)*8);
    #pragma unroll
    for (int f = 0; f < 4; ++f)
      bv[f] = *(const short8*)(lds + b*32768 + 16384 + (wn>>1)*8192 + (ks*4+lk)*1024
                               + ((wn&1)*64 + f*16 + lm)*8);
    __builtin_amdgcn_s_setprio(1);
    #pragma unroll
    for (int i = 0; i < 8; ++i)
      #pragma unroll
      for (int j = 0; j < 4; ++j)
        acc[i][j] = __builtin_amdgcn_mfma_f32_16x16x32_bf16(av[i], bv[j], acc[i][j], 0, 0, 0);
    __builtin_amdgcn_s_setprio(0);
    if (n + 2 < 2*NKT)      { VMCNT(4); BAR(); }
    else if (n + 1 < 2*NKT) { VMCNT(0); BAR(); }
  }
}

// ---------------------------------------------------------------------------
// K0: convert x / W1 / W2 / W3 into bf16 frag-ready layouts.
// ---------------------------------------------------------------------------
__global__ __launch_bounds__(256)
void k_convert(const float* __restrict__ x,  const float* __restrict__ W1,
               const float* __restrict__ W2, const float* __restrict__ W3,
               short* __restrict__ xf, short* __restrict__ w1f,
               short* __restrict__ w2f, short* __restrict__ w3f)
{
  const int gi = blockIdx.x * 256 + threadIdx.x;
  if (gi < 2097152) {                       // xf: [bt64][kt32] tiles of x
    const int t = gi >> 10, r = gi & 1023;
    const int bt = t >> 5, kt = t & 31;
    const int kg = r >> 7, p = r & 127;
    const float* src = x + (size_t)(bt*128 + p)*2048 + kt*64 + kg*8;
    const float4 v0 = *(const float4*)src;
    const float4 v1 = *(const float4*)(src + 4);
    short8 o;
    o[0]=f2bf(v0.x); o[1]=f2bf(v0.y); o[2]=f2bf(v0.z); o[3]=f2bf(v0.w);
    o[4]=f2bf(v1.x); o[5]=f2bf(v1.y); o[6]=f2bf(v1.z); o[7]=f2bf(v1.w);
    *(short8*)(xf + (size_t)gi*8) = o;
  } else if (gi < 2097152 + 262144) {       // w1f: [e8][kt32] tiles of W1[e]
    const int g = gi - 2097152;
    const int t = g >> 10, r = g & 1023;
    const int e = t >> 5, kt = t & 31;
    const int kg = r >> 7, p = r & 127;
    const int k0 = kt*64 + kg*8;
    short8 o;
    #pragma unroll
    for (int j = 0; j < 8; ++j)
      o[j] = f2bf(W1[(size_t)e*262144 + (size_t)(k0 + j)*128 + p]);
    *(short8*)(w1f + (size_t)g*8) = o;
  } else if (gi < 2097152 + 262144 + 16384) { // w2f: [e8][kt2] tiles of W2[e]
    const int g = gi - (2097152 + 262144);
    const int t = g >> 10, r = g & 1023;
    const int e = t >> 1, kt = t & 1;
    const int kg = r >> 7, p = r & 127;
    const int k0 = kt*64 + kg*8;
    short8 o;
    #pragma unroll
    for (int j = 0; j < 8; ++j)
      o[j] = f2bf(W2[(size_t)e*16384 + (size_t)(k0 + j)*128 + p]);
    *(short8*)(w2f + (size_t)g*8) = o;
  } else if (gi < 2637824) {                // w3f: [nt16][kt16] tiles of W3flat
    const int g = gi - 2375680;
    const int t = g >> 10, r = g & 1023;
    const int nt = t >> 4, kt = t & 15;
    const int kg = r >> 7, p = r & 127;
    const int k0 = kt*64 + kg*8;
    short8 o;
    #pragma unroll
    for (int j = 0; j < 8; ++j) {
      const int k = k0 + j;                 // k = e*128 + h
      o[j] = f2bf(W3[(size_t)(k >> 7)*262144 + (size_t)(k & 127)*2048 + nt*128 + p]);
    }
    *(short8*)(w3f + (size_t)g*8) = o;
  }
}

// ---------------------------------------------------------------------------
// K1: gate softmax.  One wave per row, fp32 end-to-end.
// ---------------------------------------------------------------------------
__global__ __launch_bounds__(256)
void k_gate(const float* __restrict__ x, const float* __restrict__ gw,
            const float* __restrict__ gb, float* __restrict__ gates)
{
  const int wid = threadIdx.x >> 6, lane = threadIdx.x & 63;
  const int row = blockIdx.x * 4 + wid;
  const float* xr = x + (size_t)row * 2048;
  float acc[8] = {0.f,0.f,0.f,0.f,0.f,0.f,0.f,0.f};
  for (int it = 0; it < 32; ++it) {
    const int k = it*64 + lane;
    const float xv = xr[k];
    const float4 g0 = *(const float4*)(gw + (size_t)k*8);
    const float4 g1 = *(const float4*)(gw + (size_t)k*8 + 4);
    acc[0] += xv*g0.x; acc[1] += xv*g0.y; acc[2] += xv*g0.z; acc[3] += xv*g0.w;
    acc[4] += xv*g1.x; acc[5] += xv*g1.y; acc[6] += xv*g1.z; acc[7] += xv*g1.w;
  }
  #pragma unroll
  for (int e = 0; e < 8; ++e) {
    #pragma unroll
    for (int d = 1; d < 64; d <<= 1)
      acc[e] += __shfl_xor(acc[e], d, 64);
  }
  if (lane == 0) {
    float lg[8], mx = -1e30f;
    #pragma unroll
    for (int e = 0; e < 8; ++e) { lg[e] = acc[e] + gb[e]; mx = fmaxf(mx, lg[e]); }
    float s = 0.f;
    #pragma unroll
    for (int e = 0; e < 8; ++e) { lg[e] = __expf(lg[e] - mx); s += lg[e]; }
    const float inv = 1.f / s;
    #pragma unroll
    for (int e = 0; e < 8; ++e) gates[(size_t)row*8 + e] = lg[e] * inv;
  }
}

// ---------------------------------------------------------------------------
// K2: GEMM1 split-K.  256 blocks: b -> {BT 0..31, NT 0..3, kh 0..1} XCD-chunked.
// Block: rows BT*256, cols NT*256 (expert pair), K-half kh*1024 (NKT=16).
// Writes bf16 partial p[kh][8192][1024].
// ---------------------------------------------------------------------------
__global__ __launch_bounds__(512, 2)
void k_gemm1s(const short* __restrict__ xf, const short* __restrict__ w1f,
              short* __restrict__ p)
{
  __shared__ short lds[65536];   // 128 KB
  const int b = blockIdx.x;
  const int xcd = b & 7, idx = b >> 3;
  const int BT = xcd*4 + (idx >> 3);      // 0..31
  const int rem = idx & 7;
  const int NT = rem >> 1, kh = rem & 1;  // 0..3, 0..1

  f32x4 acc[8][4] = {};
  core256<16>(xf  + ((size_t)(BT*2)  *32 + kh*16)*8192,
              xf  + ((size_t)(BT*2+1)*32 + kh*16)*8192,
              w1f + ((size_t)(2*NT)  *32 + kh*16)*8192,
              w1f + ((size_t)(2*NT+1)*32 + kh*16)*8192,
              lds, acc);

  const int tid = threadIdx.x, lane = tid & 63, wid = tid >> 6;
  const int wm = wid >> 2, wn = wid & 3, lm = lane & 15, lr = lane >> 4;
  short* pd = p + (size_t)kh*8388608;
  #pragma unroll
  for (int fm = 0; fm < 8; ++fm)
  #pragma unroll
  for (int i = 0; i < 4; ++i) {
    const int m = BT*256 + wm*128 + fm*16 + lr*4 + i;
    #pragma unroll
    for (int fn = 0; fn < 4; ++fn) {
      const int n = NT*256 + wn*64 + fn*16 + lm;
      pd[(size_t)m*1024 + n] = f2bf(acc[fm][fn][i]);
    }
  }
}

// ---------------------------------------------------------------------------
// K3: merge partials -> silu(h1) -> GEMM2 -> silu -> gate-scale -> h2gf frag.
// grid (64, 8): 128-row block x expert.  256 thr, 4 waves (2x2), wave 64x64.
// LDS 64KB: h1 frag @[0,16384), W2 frag @[16384,32768).
// ---------------------------------------------------------------------------
__global__ __launch_bounds__(256, 2)
void k_gemm2m(const short* __restrict__ p, const short* __restrict__ w2f,
              const float* __restrict__ b1, const float* __restrict__ b2,
              const float* __restrict__ gates, short* __restrict__ h2gf)
{
  __shared__ short lds[32768];
  const int bt2 = blockIdx.x, e = blockIdx.y;
  const int tid = threadIdx.x;
  const int wlds = (tid & ~63) * 8;

  // stage W2[e] (32 KB)
  #pragma unroll
  for (int q = 0; q < 8; ++q)
    gload_lds16(w2f + (size_t)e*16384 + q*2048 + tid*8,
                lds + 16384 + q*2048 + wlds);

  // merge p0+p1 + b1, silu, write h1 frag to LDS
  #pragma unroll
  for (int u = 0; u < 8; ++u) {
    const int g = u*256 + tid;              // 0..2047
    const int m = g >> 4, hg = g & 15;
    const size_t src = (size_t)(bt2*128 + m)*1024 + e*128 + hg*8;
    const short8 a = *(const short8*)(p + src);
    const short8 c = *(const short8*)(p + 8388608 + src);
    short8 o;
    #pragma unroll
    for (int j = 0; j < 8; ++j) {
      const float v = bf2f(a[j]) + bf2f(c[j]) + b1[e*128 + hg*8 + j];
      o[j] = f2bf(silu_f(v));
    }
    *(short8*)(lds + (hg>>3)*8192 + (hg&7)*1024 + m*8) = o;
  }
  VMCNT(0);
  __syncthreads();

  // GEMM2: h2 = h1 @ W2[e], K=128
  const int lane = tid & 63, wid = tid >> 6;
  const int wr = wid >> 1, wc = wid & 1, lm = lane & 15, lk = lane >> 4, lr = lane >> 4;
  f32x4 acc[4][4] = {};
  #pragma unroll
  for (int kt = 0; kt < 2; ++kt)
  #pragma unroll
  for (int ks = 0; ks < 2; ++ks) {
    short8 av[4], bv[4];
    #pragma unroll
    for (int f = 0; f < 4; ++f)
      av[f] = *(const short8*)(lds + kt*8192 + (ks*4+lk)*1024 + (wr*64 + f*16 + lm)*8);
    #pragma unroll
    for (int f = 0; f < 4; ++f)
      bv[f] = *(const short8*)(lds + 16384 + kt*8192 + (ks*4+lk)*1024 + (wc*64 + f*16 + lm)*8);
    #pragma unroll
    for (int i = 0; i < 4; ++i)
      #pragma unroll
      for (int j = 0; j < 4; ++j)
        acc[i][j] = __builtin_amdgcn_mfma_f32_16x16x32_bf16(av[i], bv[j], acc[i][j], 0, 0, 0);
  }
  __syncthreads();   // done reading h1 region; reuse for h2 staging

  #pragma unroll
  for (int fm = 0; fm < 4; ++fm)
  #pragma unroll
  for (int i = 0; i < 4; ++i) {
    const int m = wr*64 + fm*16 + lr*4 + i;
    const float g = gates[(size_t)(bt2*128 + m)*8 + e];
    #pragma unroll
    for (int fn = 0; fn < 4; ++fn) {
      const int h = wc*64 + fn*16 + lm;
      const float v = silu_f(acc[fm][fn][i] + b2[e*128 + h]) * g;
      lds[(h>>6)*8192 + ((h>>3)&7)*1024 + m*8 + (h&7)] = f2bf(v);
    }
  }
  __syncthreads();

  // dump h2 frag tiles: tile (bt2*16 + e*2 + t2)
  #pragma unroll
  for (int q = 0; q < 8; ++q) {
    const int g = q*256 + tid;              // 0..2047
    const int li = g*8;
    const int t2 = li >> 13, o = li & 8191;
    *(short8*)(h2gf + ((size_t)bt2*16 + e*2 + t2)*8192 + o) = *(const short8*)(lds + li);
  }
}

// ---------------------------------------------------------------------------
// K4: out = h2g @ W3flat + gates @ b3.  256 blocks, 256x256, NKT=16.
// ---------------------------------------------------------------------------
__global__ __launch_bounds__(512, 2)
void k_gemm3(const short* __restrict__ h2gf, const short* __restrict__ w3f,
             const float* __restrict__ b3, const float* __restrict__ gates,
             float* __restrict__ out)
{
  __shared__ short lds[65536];   // 128 KB
  const int wg = blockIdx.x;
  const int xcd = wg & 7, idx = wg >> 3;
  const int bt = xcd*4 + (idx & 3);       // 0..31
  const int nt = idx >> 2;                // 0..7

  f32x4 acc[8][4] = {};
  core256<16>(h2gf + (size_t)(bt*2)  *16*8192,
              h2gf + (size_t)(bt*2+1)*16*8192,
              w3f  + (size_t)(2*nt)  *16*8192,
              w3f  + (size_t)(2*nt+1)*16*8192,
              lds, acc);

  const int tid = threadIdx.x, lane = tid & 63, wid = tid >> 6;
  const int wm = wid >> 2, wn = wid & 3, lm = lane & 15, lr = lane >> 4;
  float b3c[4][8];
  #pragma unroll
  for (int fn = 0; fn < 4; ++fn) {
    const int n = nt*256 + wn*64 + fn*16 + lm;
    #pragma unroll
    for (int e = 0; e < 8; ++e) b3c[fn][e] = b3[(size_t)e*D_SZ + n];
  }
  #pragma unroll
  for (int fm = 0; fm < 8; ++fm)
  #pragma unroll
  for (int i = 0; i < 4; ++i) {
    const int m = bt*256 + wm*128 + fm*16 + lr*4 + i;
    const float4 ga  = *(const float4*)(gates + (size_t)m*8);
    const float4 gbv = *(const float4*)(gates + (size_t)m*8 + 4);
    #pragma unroll
    for (int fn = 0; fn < 4; ++fn) {
      const int n = nt*256 + wn*64 + fn*16 + lm;
      const float bias = ga.x*b3c[fn][0] + ga.y*b3c[fn][1] + ga.z*b3c[fn][2] + ga.w*b3c[fn][3]
                       + gbv.x*b3c[fn][4] + gbv.y*b3c[fn][5] + gbv.z*b3c[fn][6] + gbv.w*b3c[fn][7];
      out[(size_t)m*D_SZ + n] = acc[fm][fn][i] + bias;
    }
  }
}

// ---------------------------------------------------------------------------
extern "C" void kernel_launch(void* const* d_in, const int* in_sizes, int n_in,
                              void* d_out, int out_size, void* d_ws, size_t ws_size,
                              hipStream_t stream)
{
  (void)in_sizes; (void)n_in; (void)out_size; (void)ws_size;
  const float* x  = (const float*)d_in[0];
  const float* gw = (const float*)d_in[1];
  const float* gb = (const float*)d_in[2];
  const float* W1 = (const float*)d_in[3];
  const float* b1 = (const float*)d_in[4];
  const float* W2 = (const float*)d_in[5];
  const float* b2 = (const float*)d_in[6];
  const float* W3 = (const float*)d_in[7];
  const float* b3 = (const float*)d_in[8];
  float* out = (float*)d_out;

  char* ws = (char*)d_ws;
  short* xf    = (short*)ws;  ws += (size_t)B_SZ*D_SZ*2;          // 33.5 MB
  short* w1f   = (short*)ws;  ws += (size_t)E_SZ*D_SZ*H_SZ*2;     //  4.2 MB
  short* w2f   = (short*)ws;  ws += (size_t)E_SZ*H_SZ*H_SZ*2;     //  0.26 MB
  short* w3f   = (short*)ws;  ws += (size_t)E_SZ*H_SZ*D_SZ*2;     //  4.2 MB
  float* gates = (float*)ws;  ws += (size_t)B_SZ*E_SZ*4;          //  0.26 MB
  short* p     = (short*)ws;  ws += (size_t)2*B_SZ*1024*2;        // 33.5 MB
  short* h2gf  = (short*)ws;  ws += (size_t)B_SZ*E_SZ*H_SZ*2;     // 16.8 MB

  k_convert<<<dim3(10304), dim3(256), 0, stream>>>(x, W1, W2, W3, xf, w1f, w2f, w3f);
  k_gate   <<<dim3(2048),  dim3(256), 0, stream>>>(x, gw, gb, gates);
  k_gemm1s <<<dim3(256),   dim3(512), 0, stream>>>(xf, w1f, p);
  k_gemm2m <<<dim3(64, 8), dim3(256), 0, stream>>>(p, w2f, b1, b2, gates, h2gf);
  k_gemm3  <<<dim3(256),   dim3(512), 0, stream>>>(h2gf, w3f, b3, gates, out);
}

// Round 5
// 149.093 us; speedup vs baseline: 1.0114x; 1.0114x over previous
//
#include <hip/hip_runtime.h>

// ---------------------------------------------------------------------------
// MoE with adaptive gate, B=8192 D=2048 E=8 H=128, fp32 in/out, bf16 MFMA core
// GEMM1 (split-K) and GEMM3: 256x256 blocks with the 8-phase counted-vmcnt
// pipeline (T3+T4+T5): 4 half-tile LDS buffers, 2 phases per half-K-tile,
// vmcnt(8) once per half-tile, 16-MFMA clusters under setprio.
// ---------------------------------------------------------------------------

typedef __attribute__((ext_vector_type(8))) short short8;   // 8 bf16 (4 VGPRs)
typedef __attribute__((ext_vector_type(4))) float f32x4;    // MFMA C/D

#define B_SZ 8192
#define D_SZ 2048
#define E_SZ 8
#define H_SZ 128

#define VMCNT(n) asm volatile("s_waitcnt vmcnt(" #n ")" ::: "memory")
#define LGKM0()  asm volatile("s_waitcnt lgkmcnt(0)" ::: "memory")
#define SB0()    __builtin_amdgcn_sched_barrier(0)
#define BAR()    __builtin_amdgcn_s_barrier()

__device__ __forceinline__ short f2bf(float f) {
  unsigned u = __builtin_bit_cast(unsigned, f);
  unsigned r = (u + 0x7fffu + ((u >> 16) & 1u)) >> 16;   // RNE
  return (short)r;
}

__device__ __forceinline__ float bf2f(short s) {
  return __builtin_bit_cast(float, (unsigned)((unsigned short)s) << 16);
}

__device__ __forceinline__ float silu_f(float v) {
  return v / (1.f + __expf(-v));
}

__device__ __forceinline__ void gload_lds16(const void* g, void* l) {
  __builtin_amdgcn_global_load_lds(
      (const __attribute__((address_space(1))) void*)g,
      (__attribute__((address_space(3))) void*)l,
      16, 0, 0);
}

// ---------------------------------------------------------------------------
// 8-phase 256x256 core.  512 thr, 8 waves (2M x 4N), wave-out 128x64, acc[8][4].
// 4 streams (A0,A1 row-halves; B0,B1 col-halves), frag tiles of 8192 shorts:
// elem = kg*1024 + p*8 + j, k = tau*64 + kg*8 + j.
// Staging unit = half-K-tile eta (K=32): 4 x global_load_lds(16B)/thread.
// LDS = 4 half-tile buffers x 32KB (A0|A1|B0|B1 x 8KB) = 128 KB.
// Pipeline: during half-tile eta issue stages for eta+3; vmcnt(8) at the end
// of eta retires eta+1's 4 loads (12 in flight steady-state, never drained).
// Per half-tile: 2 phases; each = {ds_reads || 2 stage-issues -> bar ->
// lgkm0 -> setprio(1) 16 MFMA setprio(0) -> bar}.
// ---------------------------------------------------------------------------
template<int NKT>
__device__ __forceinline__ void core256p(const short* __restrict__ A0,
                                         const short* __restrict__ A1,
                                         const short* __restrict__ B0,
                                         const short* __restrict__ B1,
                                         short* lds, f32x4 acc[8][4])
{
  const int tid  = threadIdx.x;
  const int lane = tid & 63;
  const int wid  = tid >> 6;
  const int wm = wid >> 2, wn = wid & 3;
  const int lm = lane & 15, lk = lane >> 4;
  const int wl = (tid & ~63) * 8;

  short8 av[8], bv[4];

  auto STAGE2 = [&](int eta, int half) {     // 2 of the 4 loads of half-tile eta
    const int tau = eta >> 1, ks = eta & 1, hb = eta & 3;
    const size_t go = (size_t)tau*8192 + ks*4096 + tid*8;
    short* lo = lds + hb*16384 + wl;
    if (half == 0) {
      gload_lds16(A0 + go, lo);
      gload_lds16(A1 + go, lo + 4096);
    } else {
      gload_lds16(B0 + go, lo + 8192);
      gload_lds16(B1 + go, lo + 12288);
    }
  };
  auto RD_A = [&](int eta) {                 // 8 x ds_read_b128
    const short* p = lds + (eta & 3)*16384 + wm*4096 + lk*1024 + lm*8;
    #pragma unroll
    for (int f = 0; f < 8; ++f) av[f] = *(const short8*)(p + f*128);
  };
  auto RD_B2 = [&](int eta, int nh) {        // 2 x ds_read_b128 (nh literal)
    const short* p = lds + (eta & 3)*16384 + 8192 + (wn >> 1)*4096 + lk*1024
                   + ((wn & 1)*64 + nh*32 + lm)*8;
    bv[nh*2]     = *(const short8*)(p);
    bv[nh*2 + 1] = *(const short8*)(p + 128);
  };
  auto MFMA2 = [&](int nh) {                 // 16 MFMA, one 2-col quadrant
    __builtin_amdgcn_s_setprio(1);
    #pragma unroll
    for (int i = 0; i < 8; ++i) {
      acc[i][nh*2]     = __builtin_amdgcn_mfma_f32_16x16x32_bf16(av[i], bv[nh*2],     acc[i][nh*2],     0, 0, 0);
      acc[i][nh*2 + 1] = __builtin_amdgcn_mfma_f32_16x16x32_bf16(av[i], bv[nh*2 + 1], acc[i][nh*2 + 1], 0, 0, 0);
    }
    __builtin_amdgcn_s_setprio(0);
  };
  auto HALF = [&](int eta, bool stg) {
    // phase A
    RD_A(eta); RD_B2(eta, 0);
    if (stg) STAGE2(eta + 3, 0);
    BAR(); LGKM0(); SB0();
    MFMA2(0);
    SB0(); BAR();
    // phase B
    RD_B2(eta, 1);
    if (stg) STAGE2(eta + 3, 1);
    BAR(); LGKM0(); SB0();
    MFMA2(1);
    SB0();
  };

  // prologue: half-tiles 0,1,2 in flight (12 loads); retire 0's 4.
  STAGE2(0, 0); STAGE2(0, 1);
  STAGE2(1, 0); STAGE2(1, 1);
  STAGE2(2, 0); STAGE2(2, 1);
  VMCNT(8); BAR(); SB0();

  for (int eta = 0; eta < 2*NKT - 3; ++eta) {
    HALF(eta, true);
    VMCNT(8); BAR(); SB0();
  }
  HALF(2*NKT - 3, false); VMCNT(4); BAR(); SB0();
  HALF(2*NKT - 2, false); VMCNT(0); BAR(); SB0();
  HALF(2*NKT - 1, false);
}

// ---------------------------------------------------------------------------
// K0: convert x / W1 / W2 / W3 into bf16 frag-ready layouts.
// ---------------------------------------------------------------------------
__global__ __launch_bounds__(256)
void k_convert(const float* __restrict__ x,  const float* __restrict__ W1,
               const float* __restrict__ W2, const float* __restrict__ W3,
               short* __restrict__ xf, short* __restrict__ w1f,
               short* __restrict__ w2f, short* __restrict__ w3f)
{
  const int gi = blockIdx.x * 256 + threadIdx.x;
  if (gi < 2097152) {                       // xf: [bt64][kt32] tiles of x
    const int t = gi >> 10, r = gi & 1023;
    const int bt = t >> 5, kt = t & 31;
    const int kg = r >> 7, p = r & 127;
    const float* src = x + (size_t)(bt*128 + p)*2048 + kt*64 + kg*8;
    const float4 v0 = *(const float4*)src;
    const float4 v1 = *(const float4*)(src + 4);
    short8 o;
    o[0]=f2bf(v0.x); o[1]=f2bf(v0.y); o[2]=f2bf(v0.z); o[3]=f2bf(v0.w);
    o[4]=f2bf(v1.x); o[5]=f2bf(v1.y); o[6]=f2bf(v1.z); o[7]=f2bf(v1.w);
    *(short8*)(xf + (size_t)gi*8) = o;
  } else if (gi < 2097152 + 262144) {       // w1f: [e8][kt32] tiles of W1[e]
    const int g = gi - 2097152;
    const int t = g >> 10, r = g & 1023;
    const int e = t >> 5, kt = t & 31;
    const int kg = r >> 7, p = r & 127;
    const int k0 = kt*64 + kg*8;
    short8 o;
    #pragma unroll
    for (int j = 0; j < 8; ++j)
      o[j] = f2bf(W1[(size_t)e*262144 + (size_t)(k0 + j)*128 + p]);
    *(short8*)(w1f + (size_t)g*8) = o;
  } else if (gi < 2097152 + 262144 + 16384) { // w2f: [e8][kt2] tiles of W2[e]
    const int g = gi - (2097152 + 262144);
    const int t = g >> 10, r = g & 1023;
    const int e = t >> 1, kt = t & 1;
    const int kg = r >> 7, p = r & 127;
    const int k0 = kt*64 + kg*8;
    short8 o;
    #pragma unroll
    for (int j = 0; j < 8; ++j)
      o[j] = f2bf(W2[(size_t)e*16384 + (size_t)(k0 + j)*128 + p]);
    *(short8*)(w2f + (size_t)g*8) = o;
  } else if (gi < 2637824) {                // w3f: [nt16][kt16] tiles of W3flat
    const int g = gi - 2375680;
    const int t = g >> 10, r = g & 1023;
    const int nt = t >> 4, kt = t & 15;
    const int kg = r >> 7, p = r & 127;
    const int k0 = kt*64 + kg*8;
    short8 o;
    #pragma unroll
    for (int j = 0; j < 8; ++j) {
      const int k = k0 + j;                 // k = e*128 + h
      o[j] = f2bf(W3[(size_t)(k >> 7)*262144 + (size_t)(k & 127)*2048 + nt*128 + p]);
    }
    *(short8*)(w3f + (size_t)g*8) = o;
  }
}

// ---------------------------------------------------------------------------
// K1: gate softmax.  One wave per row, fp32 end-to-end.
// ---------------------------------------------------------------------------
__global__ __launch_bounds__(256)
void k_gate(const float* __restrict__ x, const float* __restrict__ gw,
            const float* __restrict__ gb, float* __restrict__ gates)
{
  const int wid = threadIdx.x >> 6, lane = threadIdx.x & 63;
  const int row = blockIdx.x * 4 + wid;
  const float* xr = x + (size_t)row * 2048;
  float acc[8] = {0.f,0.f,0.f,0.f,0.f,0.f,0.f,0.f};
  for (int it = 0; it < 32; ++it) {
    const int k = it*64 + lane;
    const float xv = xr[k];
    const float4 g0 = *(const float4*)(gw + (size_t)k*8);
    const float4 g1 = *(const float4*)(gw + (size_t)k*8 + 4);
    acc[0] += xv*g0.x; acc[1] += xv*g0.y; acc[2] += xv*g0.z; acc[3] += xv*g0.w;
    acc[4] += xv*g1.x; acc[5] += xv*g1.y; acc[6] += xv*g1.z; acc[7] += xv*g1.w;
  }
  #pragma unroll
  for (int e = 0; e < 8; ++e) {
    #pragma unroll
    for (int d = 1; d < 64; d <<= 1)
      acc[e] += __shfl_xor(acc[e], d, 64);
  }
  if (lane == 0) {
    float lg[8], mx = -1e30f;
    #pragma unroll
    for (int e = 0; e < 8; ++e) { lg[e] = acc[e] + gb[e]; mx = fmaxf(mx, lg[e]); }
    float s = 0.f;
    #pragma unroll
    for (int e = 0; e < 8; ++e) { lg[e] = __expf(lg[e] - mx); s += lg[e]; }
    const float inv = 1.f / s;
    #pragma unroll
    for (int e = 0; e < 8; ++e) gates[(size_t)row*8 + e] = lg[e] * inv;
  }
}

// ---------------------------------------------------------------------------
// K2: GEMM1 split-K.  256 blocks: b -> {BT 0..31, NT 0..3, kh 0..1} XCD-chunked.
// Block: rows BT*256, cols NT*256 (expert pair), K-half kh*1024 (NKT=16).
// Writes bf16 partial p[kh][8192][1024].
// ---------------------------------------------------------------------------
__global__ __launch_bounds__(512, 2)
void k_gemm1s(const short* __restrict__ xf, const short* __restrict__ w1f,
              short* __restrict__ p)
{
  __shared__ short lds[65536];   // 128 KB
  const int b = blockIdx.x;
  const int xcd = b & 7, idx = b >> 3;
  const int BT = xcd*4 + (idx >> 3);      // 0..31
  const int rem = idx & 7;
  const int NT = rem >> 1, kh = rem & 1;  // 0..3, 0..1

  f32x4 acc[8][4] = {};
  core256p<16>(xf  + ((size_t)(BT*2)  *32 + kh*16)*8192,
               xf  + ((size_t)(BT*2+1)*32 + kh*16)*8192,
               w1f + ((size_t)(2*NT)  *32 + kh*16)*8192,
               w1f + ((size_t)(2*NT+1)*32 + kh*16)*8192,
               lds, acc);

  const int tid = threadIdx.x, lane = tid & 63, wid = tid >> 6;
  const int wm = wid >> 2, wn = wid & 3, lm = lane & 15, lr = lane >> 4;
  short* pd = p + (size_t)kh*8388608;
  #pragma unroll
  for (int fm = 0; fm < 8; ++fm)
  #pragma unroll
  for (int i = 0; i < 4; ++i) {
    const int m = BT*256 + wm*128 + fm*16 + lr*4 + i;
    #pragma unroll
    for (int fn = 0; fn < 4; ++fn) {
      const int n = NT*256 + wn*64 + fn*16 + lm;
      pd[(size_t)m*1024 + n] = f2bf(acc[fm][fn][i]);
    }
  }
}

// ---------------------------------------------------------------------------
// K3: merge partials -> silu(h1) -> GEMM2 -> silu -> gate-scale -> h2gf frag.
// grid (64, 8): 128-row block x expert.  256 thr, 4 waves (2x2), wave 64x64.
// LDS 64KB: h1 frag @[0,16384), W2 frag @[16384,32768).
// ---------------------------------------------------------------------------
__global__ __launch_bounds__(256, 2)
void k_gemm2m(const short* __restrict__ p, const short* __restrict__ w2f,
              const float* __restrict__ b1, const float* __restrict__ b2,
              const float* __restrict__ gates, short* __restrict__ h2gf)
{
  __shared__ short lds[32768];
  const int bt2 = blockIdx.x, e = blockIdx.y;
  const int tid = threadIdx.x;
  const int wlds = (tid & ~63) * 8;

  // stage W2[e] (32 KB)
  #pragma unroll
  for (int q = 0; q < 8; ++q)
    gload_lds16(w2f + (size_t)e*16384 + q*2048 + tid*8,
                lds + 16384 + q*2048 + wlds);

  // merge p0+p1 + b1, silu, write h1 frag to LDS
  #pragma unroll
  for (int u = 0; u < 8; ++u) {
    const int g = u*256 + tid;              // 0..2047
    const int m = g >> 4, hg = g & 15;
    const size_t src = (size_t)(bt2*128 + m)*1024 + e*128 + hg*8;
    const short8 a = *(const short8*)(p + src);
    const short8 c = *(const short8*)(p + 8388608 + src);
    short8 o;
    #pragma unroll
    for (int j = 0; j < 8; ++j) {
      const float v = bf2f(a[j]) + bf2f(c[j]) + b1[e*128 + hg*8 + j];
      o[j] = f2bf(silu_f(v));
    }
    *(short8*)(lds + (hg>>3)*8192 + (hg&7)*1024 + m*8) = o;
  }
  VMCNT(0);
  __syncthreads();

  // GEMM2: h2 = h1 @ W2[e], K=128
  const int lane = tid & 63, wid = tid >> 6;
  const int wr = wid >> 1, wc = wid & 1, lm = lane & 15, lk = lane >> 4, lr = lane >> 4;
  f32x4 acc[4][4] = {};
  #pragma unroll
  for (int kt = 0; kt < 2; ++kt)
  #pragma unroll
  for (int ks = 0; ks < 2; ++ks) {
    short8 av[4], bv[4];
    #pragma unroll
    for (int f = 0; f < 4; ++f)
      av[f] = *(const short8*)(lds + kt*8192 + (ks*4+lk)*1024 + (wr*64 + f*16 + lm)*8);
    #pragma unroll
    for (int f = 0; f < 4; ++f)
      bv[f] = *(const short8*)(lds + 16384 + kt*8192 + (ks*4+lk)*1024 + (wc*64 + f*16 + lm)*8);
    #pragma unroll
    for (int i = 0; i < 4; ++i)
      #pragma unroll
      for (int j = 0; j < 4; ++j)
        acc[i][j] = __builtin_amdgcn_mfma_f32_16x16x32_bf16(av[i], bv[j], acc[i][j], 0, 0, 0);
  }
  __syncthreads();   // done reading h1 region; reuse for h2 staging

  #pragma unroll
  for (int fm = 0; fm < 4; ++fm)
  #pragma unroll
  for (int i = 0; i < 4; ++i) {
    const int m = wr*64 + fm*16 + lr*4 + i;
    const float g = gates[(size_t)(bt2*128 + m)*8 + e];
    #pragma unroll
    for (int fn = 0; fn < 4; ++fn) {
      const int h = wc*64 + fn*16 + lm;
      const float v = silu_f(acc[fm][fn][i] + b2[e*128 + h]) * g;
      lds[(h>>6)*8192 + ((h>>3)&7)*1024 + m*8 + (h&7)] = f2bf(v);
    }
  }
  __syncthreads();

  // dump h2 frag tiles: tile (bt2*16 + e*2 + t2)
  #pragma unroll
  for (int q = 0; q < 8; ++q) {
    const int g = q*256 + tid;              // 0..2047
    const int li = g*8;
    const int t2 = li >> 13, o = li & 8191;
    *(short8*)(h2gf + ((size_t)bt2*16 + e*2 + t2)*8192 + o) = *(const short8*)(lds + li);
  }
}

// ---------------------------------------------------------------------------
// K4: out = h2g @ W3flat + gates @ b3.  256 blocks, 256x256, NKT=16.
// ---------------------------------------------------------------------------
__global__ __launch_bounds__(512, 2)
void k_gemm3(const short* __restrict__ h2gf, const short* __restrict__ w3f,
             const float* __restrict__ b3, const float* __restrict__ gates,
             float* __restrict__ out)
{
  __shared__ short lds[65536];   // 128 KB
  const int wg = blockIdx.x;
  const int xcd = wg & 7, idx = wg >> 3;
  const int bt = xcd*4 + (idx & 3);       // 0..31
  const int nt = idx >> 2;                // 0..7

  f32x4 acc[8][4] = {};
  core256p<16>(h2gf + (size_t)(bt*2)  *16*8192,
               h2gf + (size_t)(bt*2+1)*16*8192,
               w3f  + (size_t)(2*nt)  *16*8192,
               w3f  + (size_t)(2*nt+1)*16*8192,
               lds, acc);

  const int tid = threadIdx.x, lane = tid & 63, wid = tid >> 6;
  const int wm = wid >> 2, wn = wid & 3, lm = lane & 15, lr = lane >> 4;
  float b3c[4][8];
  #pragma unroll
  for (int fn = 0; fn < 4; ++fn) {
    const int n = nt*256 + wn*64 + fn*16 + lm;
    #pragma unroll
    for (int e = 0; e < 8; ++e) b3c[fn][e] = b3[(size_t)e*D_SZ + n];
  }
  #pragma unroll
  for (int fm = 0; fm < 8; ++fm)
  #pragma unroll
  for (int i = 0; i < 4; ++i) {
    const int m = bt*256 + wm*128 + fm*16 + lr*4 + i;
    const float4 ga  = *(const float4*)(gates + (size_t)m*8);
    const float4 gbv = *(const float4*)(gates + (size_t)m*8 + 4);
    #pragma unroll
    for (int fn = 0; fn < 4; ++fn) {
      const int n = nt*256 + wn*64 + fn*16 + lm;
      const float bias = ga.x*b3c[fn][0] + ga.y*b3c[fn][1] + ga.z*b3c[fn][2] + ga.w*b3c[fn][3]
                       + gbv.x*b3c[fn][4] + gbv.y*b3c[fn][5] + gbv.z*b3c[fn][6] + gbv.w*b3c[fn][7];
      out[(size_t)m*D_SZ + n] = acc[fm][fn][i] + bias;
    }
  }
}

// ---------------------------------------------------------------------------
extern "C" void kernel_launch(void* const* d_in, const int* in_sizes, int n_in,
                              void* d_out, int out_size, void* d_ws, size_t ws_size,
                              hipStream_t stream)
{
  (void)in_sizes; (void)n_in; (void)out_size; (void)ws_size;
  const float* x  = (const float*)d_in[0];
  const float* gw = (const float*)d_in[1];
  const float* gb = (const float*)d_in[2];
  const float* W1 = (const float*)d_in[3];
  const float* b1 = (const float*)d_in[4];
  const float* W2 = (const float*)d_in[5];
  const float* b2 = (const float*)d_in[6];
  const float* W3 = (const float*)d_in[7];
  const float* b3 = (const float*)d_in[8];
  float* out = (float*)d_out;

  char* ws = (char*)d_ws;
  short* xf    = (short*)ws;  ws += (size_t)B_SZ*D_SZ*2;          // 33.5 MB
  short* w1f   = (short*)ws;  ws += (size_t)E_SZ*D_SZ*H_SZ*2;     //  4.2 MB
  short* w2f   = (short*)ws;  ws += (size_t)E_SZ*H_SZ*H_SZ*2;     //  0.26 MB
  short* w3f   = (short*)ws;  ws += (size_t)E_SZ*H_SZ*D_SZ*2;     //  4.2 MB
  float* gates = (float*)ws;  ws += (size_t)B_SZ*E_SZ*4;          //  0.26 MB
  short* p     = (short*)ws;  ws += (size_t)2*B_SZ*1024*2;        // 33.5 MB
  short* h2gf  = (short*)ws;  ws += (size_t)B_SZ*E_SZ*H_SZ*2;     // 16.8 MB

  k_convert<<<dim3(10304), dim3(256), 0, stream>>>(x, W1, W2, W3, xf, w1f, w2f, w3f);
  k_gate   <<<dim3(2048),  dim3(256), 0, stream>>>(x, gw, gb, gates);
  k_gemm1s <<<dim3(256),   dim3(512), 0, stream>>>(xf, w1f, p);
  k_gemm2m <<<dim3(64, 8), dim3(256), 0, stream>>>(p, w2f, b1, b2, gates, h2gf);
  k_gemm3  <<<dim3(256),   dim3(512), 0, stream>>>(h2gf, w3f, b3, gates, out);
}